// Round 7
// baseline (487.954 us; speedup 1.0000x reference)
//
#include <hip/hip_runtime.h>

// SCAM for MI355X (gfx950) — v8 "two-kernel split".
// K1 proj4: streaming LN + 4 projections -> bf16 workspace (q_l*scale, q_r
//   row-major; v_l^T, v_r^T transposed), LDS-bounced for coalesced stores.
//   No softmax state -> ~85 regs, spill-free, no barrier convoy.
// K2 attn2: QK^T (frags straight from L2/L3-hot workspace), dual softmax
//   (fused per-column combine), PV from workspace, fused epilogue.
//   Only P_r / P_c^T in LDS -> 2 barriers, demand ~90 regs at (512,4).
// Fallback: if ws_size < 128 MB + 128 KB, run the proven v5-style fused
// kernel (with the fused col-combine trim).

typedef __attribute__((ext_vector_type(8))) __bf16 bf16x8;
typedef __attribute__((ext_vector_type(4))) __bf16 bf16x4;
typedef __attribute__((ext_vector_type(4))) float f4;

#define MFMA(A, B, C) __builtin_amdgcn_mfma_f32_16x16x32_bf16((A), (B), (C), 0, 0, 0)
#define SCALE_QK 0.08838834764831845f  // 128^-0.5

// XOR-swizzled LDS offset for a [128][128] bf16 slot (256 B row stride).
static __device__ __forceinline__ int eoff(int n, int k) {
  return (n << 8) + ((((k >> 3) ^ (n & 7)) << 4) | ((k & 7) << 1));
}

// Prep: transpose 4 fp32 [k][n] weight matrices to bf16 [n][k] in workspace.
__global__ void prep_w(const float* __restrict__ w0, const float* __restrict__ w1,
                       const float* __restrict__ w2, const float* __restrict__ w3,
                       __bf16* __restrict__ out) {
  int m = blockIdx.y;
  const float* src = (m == 0) ? w0 : (m == 1) ? w1 : (m == 2) ? w2 : w3;
  int t = blockIdx.x * 256 + threadIdx.x;  // 0..16383
  int k = t >> 7, n = t & 127;
  out[m * 16384 + n * 128 + k] = (__bf16)src[k * 128 + n];
}

// Load one x row (A-frag layout: row = w*16+l16, k = ks*32+quad*8+0..7),
// LayerNorm via 2 shuffles; emit BOTH ln(x) and raw-x bf16 A-fragments.
static __device__ __forceinline__ void ln_x_frags(const float* __restrict__ xp,
                                                  size_t base, const float* __restrict__ g,
                                                  const float* __restrict__ b, int row,
                                                  int quad, bf16x8* lF, bf16x8* xF) {
  float4 v[8];
#pragma unroll
  for (int t = 0; t < 8; ++t)
    v[t] = *(const float4*)(xp + base + row * 128 + (t >> 1) * 32 + quad * 8 + (t & 1) * 4);
  float s = 0.f, s2 = 0.f;
#pragma unroll
  for (int t = 0; t < 8; ++t) {
    s += v[t].x + v[t].y + v[t].z + v[t].w;
    s2 += v[t].x * v[t].x + v[t].y * v[t].y + v[t].z * v[t].z + v[t].w * v[t].w;
  }
  s += __shfl_xor(s, 16);
  s += __shfl_xor(s, 32);
  s2 += __shfl_xor(s2, 16);
  s2 += __shfl_xor(s2, 32);
  float mean = s * 0.0078125f;
  float var = s2 * 0.0078125f - mean * mean;
  float rstd = rsqrtf(var + 1e-6f);
#pragma unroll
  for (int ks = 0; ks < 4; ++ks) {
    bf16x8 lu, xu;
#pragma unroll
    for (int t = 0; t < 2; ++t) {
      float4 q = v[ks * 2 + t];
      float4 gv = *(const float4*)(g + ks * 32 + quad * 8 + t * 4);
      float4 bv = *(const float4*)(b + ks * 32 + quad * 8 + t * 4);
      xu[t * 4 + 0] = (__bf16)q.x;
      xu[t * 4 + 1] = (__bf16)q.y;
      xu[t * 4 + 2] = (__bf16)q.z;
      xu[t * 4 + 3] = (__bf16)q.w;
      lu[t * 4 + 0] = (__bf16)((q.x - mean) * rstd * gv.x + bv.x);
      lu[t * 4 + 1] = (__bf16)((q.y - mean) * rstd * gv.y + bv.y);
      lu[t * 4 + 2] = (__bf16)((q.z - mean) * rstd * gv.z + bv.z);
      lu[t * 4 + 3] = (__bf16)((q.w - mean) * rstd * gv.w + bv.w);
    }
    lF[ks] = lu;
    xF[ks] = xu;
  }
}

// Projection: out = A @ W + bias into a swizzled LDS slot.
// TRANSPOSED=0: row-major [i][c]; TRANSPOSED=1: [c][i] (for V^T).
template <int TRANSPOSED>
static __device__ __forceinline__ void proj_g(const bf16x8* aF,
                                              const __bf16* __restrict__ wTm, char* dst,
                                              const float* __restrict__ bias, float scale,
                                              int w, int l16, int quad) {
#pragma unroll 2
  for (int nt = 0; nt < 8; ++nt) {
    f4 a = {0.f, 0.f, 0.f, 0.f};
    const __bf16* wrow = wTm + (nt * 16 + l16) * 128 + quad * 8;
#pragma unroll
    for (int ks = 0; ks < 4; ++ks) {
      bf16x8 bf = *(const bf16x8*)(wrow + ks * 32);
      a = MFMA(aF[ks], bf, a);
    }
    float bs = bias[nt * 16 + l16];
    if (TRANSPOSED) {
      int c = nt * 16 + l16;
      bf16x4 u;
#pragma unroll
      for (int r = 0; r < 4; ++r) u[r] = (__bf16)((a[r] + bs) * scale);
      *(bf16x4*)(dst + eoff(c, w * 16 + quad * 4)) = u;
    } else {
#pragma unroll
      for (int r = 0; r < 4; ++r) {
        int i = w * 16 + quad * 4 + r;
        *(__bf16*)(dst + eoff(i, nt * 16 + l16)) = (__bf16)((a[r] + bs) * scale);
      }
    }
  }
}

// De-swizzle an LDS slot to linear global [n][k] bf16, fully coalesced.
static __device__ __forceinline__ void copyout(const char* slot, __bf16* __restrict__ dst,
                                               int tid) {
#pragma unroll
  for (int it = 0; it < 4; ++it) {
    int idx = it * 512 + tid;  // 2048 x 16 B chunks
    int n = idx >> 4, seg = idx & 15;
    *(uint4*)(dst + n * 128 + seg * 8) =
        *(const uint4*)(slot + (n << 8) + ((seg ^ (n & 7)) << 4));
  }
}

// ---- K1: projections -> workspace ----
__global__ __launch_bounds__(512, 4) void proj4(
    const float* __restrict__ xl, const float* __restrict__ xr,
    const float* __restrict__ gl, const float* __restrict__ bl,
    const float* __restrict__ gr, const float* __restrict__ br,
    const __bf16* __restrict__ wT, const float* __restrict__ bql,
    const float* __restrict__ bqr, const float* __restrict__ bvl,
    const float* __restrict__ bvr, __bf16* __restrict__ qlw,
    __bf16* __restrict__ qrw, __bf16* __restrict__ vtlw, __bf16* __restrict__ vtrw) {
  __shared__ char S[65536];
  char* S1 = S;
  char* S2 = S + 32768;
  int tid = threadIdx.x;
  int lane = tid & 63, w = tid >> 6;
  int quad = lane >> 4, l16 = lane & 15;
  int row = w * 16 + l16;
  size_t base = (size_t)blockIdx.x << 14;

  {
    bf16x8 lF[4], xF[4];
    ln_x_frags(xl, base, gl, bl, row, quad, lF, xF);
    proj_g<0>(lF, wT, S1, bql, SCALE_QK, w, l16, quad);          // q_l * SCALE
    proj_g<1>(xF, wT + 2 * 16384, S2, bvl, 1.0f, w, l16, quad);  // v_l^T
  }
  __syncthreads();
  copyout(S1, qlw + base, tid);
  copyout(S2, vtlw + base, tid);
  __syncthreads();
  {
    bf16x8 lF[4], xF[4];
    ln_x_frags(xr, base, gr, br, row, quad, lF, xF);
    proj_g<0>(lF, wT + 16384, S1, bqr, 1.0f, w, l16, quad);      // q_r
    proj_g<1>(xF, wT + 3 * 16384, S2, bvr, 1.0f, w, l16, quad);  // v_r^T
  }
  __syncthreads();
  copyout(S1, qrw + base, tid);
  copyout(S2, vtrw + base, tid);
}

// f = P @ V fused with epilogue; V^T B-frags straight from workspace.
static __device__ __forceinline__ void pv_epi_g(const bf16x8* pF,
                                                const __bf16* __restrict__ vws,
                                                const float* __restrict__ xp, size_t base,
                                                const float* __restrict__ scl,
                                                float* __restrict__ outp, int w, int l16,
                                                int quad) {
#pragma unroll 2
  for (int nt = 0; nt < 8; ++nt) {
    f4 a = {0.f, 0.f, 0.f, 0.f};
#pragma unroll
    for (int ks = 0; ks < 4; ++ks) {
      bf16x8 bf = *(const bf16x8*)(vws + (nt * 16 + l16) * 128 + ks * 32 + quad * 8);
      a = MFMA(pF[ks], bf, a);
    }
    int c = nt * 16 + l16;
    float sv = scl[c];
#pragma unroll
    for (int r = 0; r < 4; ++r) {
      int i = w * 16 + quad * 4 + r;
      outp[base + i * 128 + c] = xp[base + i * 128 + c] + sv * (float)a[r];
    }
  }
}

// ---- K2: QK^T + dual softmax + PV + epilogue; 2 barriers ----
__global__ __launch_bounds__(512, 4) void attn2(
    const float* __restrict__ xl, const float* __restrict__ xr,
    const __bf16* __restrict__ qlw, const __bf16* __restrict__ qrw,
    const __bf16* __restrict__ vtlw, const __bf16* __restrict__ vtrw,
    const float* __restrict__ beta, const float* __restrict__ gamma,
    float* __restrict__ out0, float* __restrict__ out1) {
  __shared__ char S[73728];  // S1 = P_r | S2 = P_c^T | colred 8 K
  char* S1 = S;
  char* S2 = S + 32768;
  float* colred0 = (float*)(S + 65536);
  float* colred1 = (float*)(S + 69632);
  int tid = threadIdx.x;
  int lane = tid & 63, w = tid >> 6;
  int quad = lane >> 4, l16 = lane & 15;
  int row = w * 16 + l16;
  size_t base = (size_t)blockIdx.x << 14;

  // A-frags of q_l (own rows, linear workspace layout).
  bf16x8 qlF[4];
#pragma unroll
  for (int ks = 0; ks < 4; ++ks)
    qlF[ks] = *(const bf16x8*)(qlw + base + row * 128 + ks * 32 + quad * 8);

  // ---- S = q_l @ q_r^T, B-frags from workspace (L2/L3-hot) ----
  f4 sacc[8];
#pragma unroll
  for (int nt = 0; nt < 8; ++nt) {
    f4 z = {0.f, 0.f, 0.f, 0.f};
    sacc[nt] = z;
  }
#pragma unroll
  for (int nt = 0; nt < 8; ++nt)
#pragma unroll
    for (int ks = 0; ks < 4; ++ks) {
      bf16x8 bf =
          *(const bf16x8*)(qrw + base + (nt * 16 + l16) * 128 + ks * 32 + quad * 8);
      sacc[nt] = MFMA(qlF[ks], bf, sacc[nt]);
    }

  // ---- row stats + P_r -> S1 (own-wave band; no barrier needed) ----
  {
    float rm[4], rinv[4];
#pragma unroll
    for (int r = 0; r < 4; ++r) {
      float m = -1e30f;
#pragma unroll
      for (int nt = 0; nt < 8; ++nt) m = fmaxf(m, sacc[nt][r]);
#pragma unroll
      for (int d = 1; d < 16; d <<= 1) m = fmaxf(m, __shfl_xor(m, d));
      float s = 0.f;
#pragma unroll
      for (int nt = 0; nt < 8; ++nt) s += __expf(sacc[nt][r] - m);
#pragma unroll
      for (int d = 1; d < 16; d <<= 1) s += __shfl_xor(s, d);
      rm[r] = m;
      rinv[r] = 1.f / s;
    }
#pragma unroll
    for (int nt = 0; nt < 8; ++nt) {
#pragma unroll
      for (int r = 0; r < 4; ++r) {
        int i = w * 16 + quad * 4 + r;
        *(__bf16*)(S1 + eoff(i, nt * 16 + l16)) =
            (__bf16)(__expf(sacc[nt][r] - rm[r]) * rinv[r]);
      }
    }
  }

  // ---- wave-local column stats -> colred ----
#pragma unroll
  for (int nt = 0; nt < 8; ++nt) {
    float m = fmaxf(fmaxf(sacc[nt][0], sacc[nt][1]), fmaxf(sacc[nt][2], sacc[nt][3]));
    m = fmaxf(m, __shfl_xor(m, 16));
    m = fmaxf(m, __shfl_xor(m, 32));
    float s = __expf(sacc[nt][0] - m) + __expf(sacc[nt][1] - m) +
              __expf(sacc[nt][2] - m) + __expf(sacc[nt][3] - m);
    s += __shfl_xor(s, 16);
    s += __shfl_xor(s, 32);
    if (quad == 0) {
      colred0[w * 128 + nt * 16 + l16] = m;
      colred1[w * 128 + nt * 16 + l16] = s;
    }
  }
  __syncthreads();  // (1) colred visible

  // ---- per-nt combine + P_c^T -> S2 (transient stats; sacc dies here) ----
#pragma unroll
  for (int nt = 0; nt < 8; ++nt) {
    int c = nt * 16 + l16;
    float m = -1e30f;
#pragma unroll
    for (int ww = 0; ww < 8; ++ww) m = fmaxf(m, colred0[ww * 128 + c]);
    float s = 0.f;
#pragma unroll
    for (int ww = 0; ww < 8; ++ww)
      s += colred1[ww * 128 + c] * __expf(colred0[ww * 128 + c] - m);
    float inv = 1.f / s;
    bf16x4 pc;
#pragma unroll
    for (int r = 0; r < 4; ++r) pc[r] = (__bf16)(__expf(sacc[nt][r] - m) * inv);
    *(bf16x4*)(S2 + eoff(c, w * 16 + quad * 4)) = pc;
  }

  // prF: own-wave P_r band (within-wave LDS ordering, no barrier).
  bf16x8 prF[4];
#pragma unroll
  for (int ks = 0; ks < 4; ++ks)
    prF[ks] = *(const bf16x8*)(S1 + eoff(row, ks * 32 + quad * 8));
  __syncthreads();  // (2) all P_c^T writes done

  // ---- PV + epilogues, V^T from workspace ----
  pv_epi_g(prF, vtrw + base, xl, base, beta, out0, w, l16, quad);

  bf16x8 pcF[4];
#pragma unroll
  for (int ks = 0; ks < 4; ++ks)
    pcF[ks] = *(const bf16x8*)(S2 + eoff(row, ks * 32 + quad * 8));
  pv_epi_g(pcF, vtlw + base, xr, base, gamma, out1, w, l16, quad);
}

// ---- Fallback: v5-style fused kernel (used when workspace is too small) ----
static __device__ __forceinline__ void x_frags(const float* __restrict__ xp, size_t base,
                                               int row, int quad, bf16x8* xF) {
#pragma unroll
  for (int ks = 0; ks < 4; ++ks) {
    bf16x8 xu;
#pragma unroll
    for (int t = 0; t < 2; ++t) {
      float4 q = *(const float4*)(xp + base + row * 128 + ks * 32 + quad * 8 + t * 4);
      xu[t * 4 + 0] = (__bf16)q.x;
      xu[t * 4 + 1] = (__bf16)q.y;
      xu[t * 4 + 2] = (__bf16)q.z;
      xu[t * 4 + 3] = (__bf16)q.w;
    }
    xF[ks] = xu;
  }
}

static __device__ __forceinline__ void pv_epi(const bf16x8* pF, const char* vslot,
                                              const float* __restrict__ xp, size_t base,
                                              const float* __restrict__ scl,
                                              float* __restrict__ outp, int w, int l16,
                                              int quad) {
#pragma unroll 2
  for (int nt = 0; nt < 8; ++nt) {
    f4 a = {0.f, 0.f, 0.f, 0.f};
#pragma unroll
    for (int ks = 0; ks < 4; ++ks) {
      bf16x8 bf = *(const bf16x8*)(vslot + eoff(nt * 16 + l16, ks * 32 + quad * 8));
      a = MFMA(pF[ks], bf, a);
    }
    int c = nt * 16 + l16;
    float sv = scl[c];
#pragma unroll
    for (int r = 0; r < 4; ++r) {
      int i = w * 16 + quad * 4 + r;
      outp[base + i * 128 + c] = xp[base + i * 128 + c] + sv * (float)a[r];
    }
  }
}

__global__ __launch_bounds__(512, 4) void scam_fused(
    const float* __restrict__ xl, const float* __restrict__ xr,
    const float* __restrict__ gl, const float* __restrict__ bl,
    const float* __restrict__ gr, const float* __restrict__ br,
    const __bf16* __restrict__ wT, const float* __restrict__ bql,
    const float* __restrict__ bqr, const float* __restrict__ bvl,
    const float* __restrict__ bvr, const float* __restrict__ beta,
    const float* __restrict__ gamma, float* __restrict__ out0,
    float* __restrict__ out1) {
  __shared__ char S[73728];
  char* S1 = S;
  char* S2 = S + 32768;
  float* colred0 = (float*)(S + 65536);
  float* colred1 = (float*)(S + 69632);
  int tid = threadIdx.x;
  int lane = tid & 63, w = tid >> 6;
  int quad = lane >> 4, l16 = lane & 15;
  int row = w * 16 + l16;
  size_t base = (size_t)blockIdx.x << 14;

  {
    bf16x8 lF[4], xF[4];
    ln_x_frags(xl, base, gl, bl, row, quad, lF, xF);
    proj_g<0>(lF, wT, S1, bql, SCALE_QK, w, l16, quad);
  }
  {
    bf16x8 lF[4], xF[4];
    ln_x_frags(xr, base, gr, br, row, quad, lF, xF);
    proj_g<0>(lF, wT + 16384, S2, bqr, 1.0f, w, l16, quad);
  }
  __syncthreads();

  bf16x8 qlF[4];
#pragma unroll
  for (int ks = 0; ks < 4; ++ks)
    qlF[ks] = *(const bf16x8*)(S1 + eoff(row, ks * 32 + quad * 8));

  f4 sacc[8];
#pragma unroll
  for (int nt = 0; nt < 8; ++nt) {
    f4 z = {0.f, 0.f, 0.f, 0.f};
    sacc[nt] = z;
  }
#pragma unroll
  for (int nt = 0; nt < 8; ++nt)
#pragma unroll
    for (int ks = 0; ks < 4; ++ks) {
      bf16x8 bf = *(const bf16x8*)(S2 + eoff(nt * 16 + l16, ks * 32 + quad * 8));
      sacc[nt] = MFMA(qlF[ks], bf, sacc[nt]);
    }

  {
    float rm[4], rinv[4];
#pragma unroll
    for (int r = 0; r < 4; ++r) {
      float m = -1e30f;
#pragma unroll
      for (int nt = 0; nt < 8; ++nt) m = fmaxf(m, sacc[nt][r]);
#pragma unroll
      for (int d = 1; d < 16; d <<= 1) m = fmaxf(m, __shfl_xor(m, d));
      float s = 0.f;
#pragma unroll
      for (int nt = 0; nt < 8; ++nt) s += __expf(sacc[nt][r] - m);
#pragma unroll
      for (int d = 1; d < 16; d <<= 1) s += __shfl_xor(s, d);
      rm[r] = m;
      rinv[r] = 1.f / s;
    }
#pragma unroll
    for (int nt = 0; nt < 8; ++nt) {
#pragma unroll
      for (int r = 0; r < 4; ++r) {
        int i = w * 16 + quad * 4 + r;
        *(__bf16*)(S1 + eoff(i, nt * 16 + l16)) =
            (__bf16)(__expf(sacc[nt][r] - rm[r]) * rinv[r]);
      }
    }
  }

  bf16x8 xrF[4];
  x_frags(xr, base, row, quad, xrF);

#pragma unroll
  for (int nt = 0; nt < 8; ++nt) {
    float m = fmaxf(fmaxf(sacc[nt][0], sacc[nt][1]), fmaxf(sacc[nt][2], sacc[nt][3]));
    m = fmaxf(m, __shfl_xor(m, 16));
    m = fmaxf(m, __shfl_xor(m, 32));
    float s = __expf(sacc[nt][0] - m) + __expf(sacc[nt][1] - m) +
              __expf(sacc[nt][2] - m) + __expf(sacc[nt][3] - m);
    s += __shfl_xor(s, 16);
    s += __shfl_xor(s, 32);
    if (quad == 0) {
      colred0[w * 128 + nt * 16 + l16] = m;
      colred1[w * 128 + nt * 16 + l16] = s;
    }
  }
  __syncthreads();  // colred visible; all QK S2 reads done

#pragma unroll
  for (int nt = 0; nt < 8; ++nt) {
    int c = nt * 16 + l16;
    float m = -1e30f;
#pragma unroll
    for (int ww = 0; ww < 8; ++ww) m = fmaxf(m, colred0[ww * 128 + c]);
    float s = 0.f;
#pragma unroll
    for (int ww = 0; ww < 8; ++ww)
      s += colred1[ww * 128 + c] * __expf(colred0[ww * 128 + c] - m);
    float inv = 1.f / s;
    bf16x4 pc;
#pragma unroll
    for (int r = 0; r < 4; ++r) pc[r] = (__bf16)(__expf(sacc[nt][r] - m) * inv);
    *(bf16x4*)(S2 + eoff(c, w * 16 + quad * 4)) = pc;
  }

  bf16x8 prF[4];
#pragma unroll
  for (int ks = 0; ks < 4; ++ks)
    prF[ks] = *(const bf16x8*)(S1 + eoff(row, ks * 32 + quad * 8));
  __syncthreads();

  proj_g<1>(xrF, wT + 3 * 16384, S1, bvr, 1.0f, w, l16, quad);
  bf16x8 xlF[4];
  x_frags(xl, base, row, quad, xlF);
  __syncthreads();

  pv_epi(prF, S1, xl, base, beta, out0, w, l16, quad);

  bf16x8 pcF[4];
#pragma unroll
  for (int ks = 0; ks < 4; ++ks)
    pcF[ks] = *(const bf16x8*)(S2 + eoff(row, ks * 32 + quad * 8));
  __syncthreads();

  proj_g<1>(xlF, wT + 2 * 16384, S2, bvl, 1.0f, w, l16, quad);
  __syncthreads();

  pv_epi(pcF, S2, xr, base, gamma, out1, w, l16, quad);
}

extern "C" void kernel_launch(void* const* d_in, const int* in_sizes, int n_in,
                              void* d_out, int out_size, void* d_ws, size_t ws_size,
                              hipStream_t stream) {
  const float* xl = (const float*)d_in[0];
  const float* xr = (const float*)d_in[1];
  const float* gl = (const float*)d_in[2];
  const float* bl = (const float*)d_in[3];
  const float* gr = (const float*)d_in[4];
  const float* br = (const float*)d_in[5];
  const float* wql = (const float*)d_in[6];
  const float* bql = (const float*)d_in[7];
  const float* wqr = (const float*)d_in[8];
  const float* bqr = (const float*)d_in[9];
  const float* wvl = (const float*)d_in[10];
  const float* bvl = (const float*)d_in[11];
  const float* wvr = (const float*)d_in[12];
  const float* bvr = (const float*)d_in[13];
  const float* beta = (const float*)d_in[14];
  const float* gamma = (const float*)d_in[15];

  __bf16* wT = (__bf16*)d_ws;          // 4 x 16384 bf16 = 128 KB
  float* out0 = (float*)d_out;         // [8,128,128,128] fp32
  float* out1 = out0 + (size_t)8 * 128 * 128 * 128;

  prep_w<<<dim3(64, 4), 256, 0, stream>>>(wql, wqr, wvl, wvr, wT);

  const size_t wbytes = 4 * 16384 * sizeof(__bf16);
  const size_t tile = (size_t)1024 * 16384;  // elements per ws tensor
  const size_t need = wbytes + 4 * tile * sizeof(__bf16);  // ~128 MB

  if (ws_size >= need) {
    __bf16* qlw = (__bf16*)((char*)d_ws + wbytes);
    __bf16* qrw = qlw + tile;
    __bf16* vtlw = qrw + tile;
    __bf16* vtrw = vtlw + tile;
    proj4<<<1024, 512, 0, stream>>>(xl, xr, gl, bl, gr, br, wT, bql, bqr, bvl, bvr,
                                    qlw, qrw, vtlw, vtrw);
    attn2<<<1024, 512, 0, stream>>>(xl, xr, qlw, qrw, vtlw, vtrw, beta, gamma, out0,
                                    out1);
  } else {
    scam_fused<<<1024, 512, 0, stream>>>(xl, xr, gl, bl, gr, br, wT, bql, bqr, bvl, bvr,
                                         beta, gamma, out0, out1);
  }
}

// Round 8
// 387.783 us; speedup vs baseline: 1.2583x; 1.2583x over previous
//
#include <hip/hip_runtime.h>

// SCAM fused kernel for MI355X (gfx950) — v9 "LSE register kill".
// Structure: v5/v7 fused kernel (1024 blocks, 8 waves x 16-row bands, two
// 32 KB LDS slots). New in v9:
//  - Log-sum-exp trick: u = exp(s - rm) packed to bf16x4 pk[8] (8 regs);
//    sacc (32 regs) DIES right after col-local stats, before the colred
//    barrier. P_c = pk * exp(rm - C_j) with C_j = cm_j + ln(colsum_j).
//  - Designated-wave column combine (wave w handles cols w*16+l16, quad 0
//    lanes), broadcasts C via 512 B colC region: combine exps 64 -> ~9.
//  - Occupancy is register-capped at 16 waves/CU for 128 total regs
//    (measured steps 64/128/256); goal is fitting 128 with NO spill.
// 7 barriers. LDS 74240 B -> 2 blocks/CU.

typedef __attribute__((ext_vector_type(8))) __bf16 bf16x8;
typedef __attribute__((ext_vector_type(4))) __bf16 bf16x4;
typedef __attribute__((ext_vector_type(4))) float f4;

#define MFMA(A, B, C) __builtin_amdgcn_mfma_f32_16x16x32_bf16((A), (B), (C), 0, 0, 0)
#define SCALE_QK 0.08838834764831845f  // 128^-0.5

// XOR-swizzled LDS offset for a [128][128] bf16 slot (256 B row stride).
static __device__ __forceinline__ int eoff(int n, int k) {
  return (n << 8) + ((((k >> 3) ^ (n & 7)) << 4) | ((k & 7) << 1));
}

// Prep: transpose 4 fp32 [k][n] weight matrices to bf16 [n][k] in workspace.
__global__ void prep_w(const float* __restrict__ w0, const float* __restrict__ w1,
                       const float* __restrict__ w2, const float* __restrict__ w3,
                       __bf16* __restrict__ out) {
  int m = blockIdx.y;
  const float* src = (m == 0) ? w0 : (m == 1) ? w1 : (m == 2) ? w2 : w3;
  int t = blockIdx.x * 256 + threadIdx.x;  // 0..16383
  int k = t >> 7, n = t & 127;
  out[m * 16384 + n * 128 + k] = (__bf16)src[k * 128 + n];
}

// LayerNorm of one row (A-frag layout), row reduce = 2 shuffles.
static __device__ __forceinline__ void ln_frags(const float* __restrict__ xp, size_t base,
                                                const float* __restrict__ g,
                                                const float* __restrict__ b, int row,
                                                int quad, bf16x8* lF) {
  float4 v[8];
#pragma unroll
  for (int t = 0; t < 8; ++t)
    v[t] = *(const float4*)(xp + base + row * 128 + (t >> 1) * 32 + quad * 8 + (t & 1) * 4);
  float s = 0.f, s2 = 0.f;
#pragma unroll
  for (int t = 0; t < 8; ++t) {
    s += v[t].x + v[t].y + v[t].z + v[t].w;
    s2 += v[t].x * v[t].x + v[t].y * v[t].y + v[t].z * v[t].z + v[t].w * v[t].w;
  }
  s += __shfl_xor(s, 16);
  s += __shfl_xor(s, 32);
  s2 += __shfl_xor(s2, 16);
  s2 += __shfl_xor(s2, 32);
  float mean = s * 0.0078125f;
  float var = s2 * 0.0078125f - mean * mean;
  float rstd = rsqrtf(var + 1e-6f);
#pragma unroll
  for (int ks = 0; ks < 4; ++ks) {
    bf16x8 lu;
#pragma unroll
    for (int t = 0; t < 2; ++t) {
      float4 q = v[ks * 2 + t];
      float4 gv = *(const float4*)(g + ks * 32 + quad * 8 + t * 4);
      float4 bv = *(const float4*)(b + ks * 32 + quad * 8 + t * 4);
      lu[t * 4 + 0] = (__bf16)((q.x - mean) * rstd * gv.x + bv.x);
      lu[t * 4 + 1] = (__bf16)((q.y - mean) * rstd * gv.y + bv.y);
      lu[t * 4 + 2] = (__bf16)((q.z - mean) * rstd * gv.z + bv.z);
      lu[t * 4 + 3] = (__bf16)((q.w - mean) * rstd * gv.w + bv.w);
    }
    lF[ks] = lu;
  }
}

// Raw x row -> bf16 A-frags (re-materialization; x is L2/L3-warm).
static __device__ __forceinline__ void x_frags(const float* __restrict__ xp, size_t base,
                                               int row, int quad, bf16x8* xF) {
#pragma unroll
  for (int ks = 0; ks < 4; ++ks) {
    bf16x8 xu;
#pragma unroll
    for (int t = 0; t < 2; ++t) {
      float4 q = *(const float4*)(xp + base + row * 128 + ks * 32 + quad * 8 + t * 4);
      xu[t * 4 + 0] = (__bf16)q.x;
      xu[t * 4 + 1] = (__bf16)q.y;
      xu[t * 4 + 2] = (__bf16)q.z;
      xu[t * 4 + 3] = (__bf16)q.w;
    }
    xF[ks] = xu;
  }
}

// Projection: out = A @ W + bias into a swizzled LDS slot. W from global
// (L1/L2-hot). unroll 2 caps live accumulators + in-flight loads.
template <int TRANSPOSED>
static __device__ __forceinline__ void proj_g(const bf16x8* aF,
                                              const __bf16* __restrict__ wTm, char* dst,
                                              const float* __restrict__ bias, float scale,
                                              int w, int l16, int quad) {
#pragma unroll 2
  for (int nt = 0; nt < 8; ++nt) {
    f4 a = {0.f, 0.f, 0.f, 0.f};
    const __bf16* wrow = wTm + (nt * 16 + l16) * 128 + quad * 8;
#pragma unroll
    for (int ks = 0; ks < 4; ++ks) {
      bf16x8 bf = *(const bf16x8*)(wrow + ks * 32);
      a = MFMA(aF[ks], bf, a);
    }
    float bs = bias[nt * 16 + l16];
    if (TRANSPOSED) {
      int c = nt * 16 + l16;
      bf16x4 u;
#pragma unroll
      for (int r = 0; r < 4; ++r) u[r] = (__bf16)((a[r] + bs) * scale);
      *(bf16x4*)(dst + eoff(c, w * 16 + quad * 4)) = u;
    } else {
#pragma unroll
      for (int r = 0; r < 4; ++r) {
        int i = w * 16 + quad * 4 + r;
        *(__bf16*)(dst + eoff(i, nt * 16 + l16)) = (__bf16)((a[r] + bs) * scale);
      }
    }
  }
}

// f = P @ V fused with epilogue: out = x + scl[c] * f, straight to global.
static __device__ __forceinline__ void pv_epi(const bf16x8* pF, const char* vslot,
                                              const float* __restrict__ xp, size_t base,
                                              const float* __restrict__ scl,
                                              float* __restrict__ outp, int w, int l16,
                                              int quad) {
#pragma unroll 2
  for (int nt = 0; nt < 8; ++nt) {
    f4 a = {0.f, 0.f, 0.f, 0.f};
#pragma unroll
    for (int ks = 0; ks < 4; ++ks) {
      bf16x8 bf = *(const bf16x8*)(vslot + eoff(nt * 16 + l16, ks * 32 + quad * 8));
      a = MFMA(pF[ks], bf, a);
    }
    int c = nt * 16 + l16;
    float sv = scl[c];
#pragma unroll
    for (int r = 0; r < 4; ++r) {
      int i = w * 16 + quad * 4 + r;
      outp[base + i * 128 + c] = xp[base + i * 128 + c] + sv * (float)a[r];
    }
  }
}

__global__ __launch_bounds__(512, 4) void scam_fused(
    const float* __restrict__ xl, const float* __restrict__ xr,
    const float* __restrict__ gl, const float* __restrict__ bl,
    const float* __restrict__ gr, const float* __restrict__ br,
    const __bf16* __restrict__ wT,  // 4 x [128][128] bf16: ql, qr, vl, vr
    const float* __restrict__ bql, const float* __restrict__ bqr,
    const float* __restrict__ bvl, const float* __restrict__ bvr,
    const float* __restrict__ beta, const float* __restrict__ gamma,
    float* __restrict__ out0, float* __restrict__ out1) {
  __shared__ char S[74240];  // S1 32K | S2 32K | colm 4K | colsum 4K | colC 512
  char* S1 = S;
  char* S2 = S + 32768;
  float* colm = (float*)(S + 65536);
  float* colsum = (float*)(S + 69632);
  float* colC = (float*)(S + 73728);  // 128 floats
  int tid = threadIdx.x;
  int lane = tid & 63, w = tid >> 6;  // wave w owns rows [16w, 16w+16)
  int quad = lane >> 4, l16 = lane & 15;
  int row = w * 16 + l16;
  size_t base = (size_t)blockIdx.x << 14;  // bh * 128*128

  // ---- Phase A/B: LN -> Q projections (staggered) ----
  {
    bf16x8 lF[4];
    ln_frags(xl, base, gl, bl, row, quad, lF);
    proj_g<0>(lF, wT, S1, bql, SCALE_QK, w, l16, quad);
  }
  {
    bf16x8 lF[4];
    ln_frags(xr, base, gr, br, row, quad, lF);
    proj_g<0>(lF, wT + 16384, S2, bqr, 1.0f, w, l16, quad);
  }
  __syncthreads();  // (1) q_l / q_r visible

  bf16x8 qlF[4];
#pragma unroll
  for (int ks = 0; ks < 4; ++ks)
    qlF[ks] = *(const bf16x8*)(S1 + eoff(row, ks * 32 + quad * 8));

  // ---- QK: S = q_l @ q_r^T ----
  f4 sacc[8];
#pragma unroll
  for (int nt = 0; nt < 8; ++nt) {
    f4 z = {0.f, 0.f, 0.f, 0.f};
    sacc[nt] = z;
  }
#pragma unroll
  for (int nt = 0; nt < 8; ++nt)
#pragma unroll
    for (int ks = 0; ks < 4; ++ks) {
      bf16x8 bf = *(const bf16x8*)(S2 + eoff(nt * 16 + l16, ks * 32 + quad * 8));
      sacc[nt] = MFMA(qlF[ks], bf, sacc[nt]);
    }

  // ---- Row stats; write P_r -> S1 (own band); pack u into pk ----
  float rm[4];
  bf16x4 pk[8];
  {
    float rinv[4];
#pragma unroll
    for (int r = 0; r < 4; ++r) {
      float m = -1e30f;
#pragma unroll
      for (int nt = 0; nt < 8; ++nt) m = fmaxf(m, sacc[nt][r]);
#pragma unroll
      for (int d = 1; d < 16; d <<= 1) m = fmaxf(m, __shfl_xor(m, d));
      float s = 0.f;
#pragma unroll
      for (int nt = 0; nt < 8; ++nt) s += __expf(sacc[nt][r] - m);
#pragma unroll
      for (int d = 1; d < 16; d <<= 1) s += __shfl_xor(s, d);
      rm[r] = m;
      rinv[r] = 1.f / s;
    }
#pragma unroll
    for (int nt = 0; nt < 8; ++nt) {
      bf16x4 u4;
#pragma unroll
      for (int r = 0; r < 4; ++r) {
        float u = __expf(sacc[nt][r] - rm[r]);
        int i = w * 16 + quad * 4 + r;
        *(__bf16*)(S1 + eoff(i, nt * 16 + l16)) = (__bf16)(u * rinv[r]);
        u4[r] = (__bf16)u;
      }
      pk[nt] = u4;
    }
  }

  // ---- Col-local stats (last use of sacc -> 32 regs die here) ----
#pragma unroll
  for (int nt = 0; nt < 8; ++nt) {
    float m = fmaxf(fmaxf(sacc[nt][0], sacc[nt][1]), fmaxf(sacc[nt][2], sacc[nt][3]));
    m = fmaxf(m, __shfl_xor(m, 16));
    m = fmaxf(m, __shfl_xor(m, 32));
    float s = __expf(sacc[nt][0] - m) + __expf(sacc[nt][1] - m) +
              __expf(sacc[nt][2] - m) + __expf(sacc[nt][3] - m);
    s += __shfl_xor(s, 16);
    s += __shfl_xor(s, 32);
    if (quad == 0) {
      colm[w * 128 + nt * 16 + l16] = m;
      colsum[w * 128 + nt * 16 + l16] = s;
    }
  }

  // Re-materialize xr frags (sacc is dead; reg room available). Latency
  // hides under the two combine barriers.
  bf16x8 xrF[4];
  x_frags(xr, base, row, quad, xrF);
  __syncthreads();  // (2) colm/colsum visible; all QK S2 reads done

  // ---- Designated-wave column combine: wave w handles cols w*16+l16 ----
  if (quad == 0) {
    int c = w * 16 + l16;
    float m = -1e30f;
#pragma unroll
    for (int ww = 0; ww < 8; ++ww) m = fmaxf(m, colm[ww * 128 + c]);
    float s = 0.f;
#pragma unroll
    for (int ww = 0; ww < 8; ++ww)
      s += colsum[ww * 128 + c] * __expf(colm[ww * 128 + c] - m);
    colC[c] = m + __logf(s);  // C_j = LSE over the column
  }
  __syncthreads();  // (3) colC visible

  // ---- P_c^T -> S2: P_c = pk * exp(rm - C_j) (LSE identity) ----
  {
    float C[8];
#pragma unroll
    for (int nt = 0; nt < 8; ++nt) C[nt] = colC[nt * 16 + l16];
#pragma unroll
    for (int nt = 0; nt < 8; ++nt) {
      bf16x4 pc;
#pragma unroll
      for (int r = 0; r < 4; ++r)
        pc[r] = (__bf16)((float)pk[nt][r] * __expf(rm[r] - C[nt]));
      *(bf16x4*)(S2 + eoff(nt * 16 + l16, w * 16 + quad * 4)) = pc;
    }
  }

  // prF: own-wave P_r band (within-wave LDS ordering, no barrier).
  bf16x8 prF[4];
#pragma unroll
  for (int ks = 0; ks < 4; ++ks)
    prF[ks] = *(const bf16x8*)(S1 + eoff(row, ks * 32 + quad * 8));
  __syncthreads();  // (4) P_c^T writes done; prF reads done -> S1 free

  // ---- V_r^T -> S1 (xrF dies); xl remat issues under the barrier ----
  proj_g<1>(xrF, wT + 3 * 16384, S1, bvr, 1.0f, w, l16, quad);
  bf16x8 xlF[4];
  x_frags(xl, base, row, quad, xlF);
  __syncthreads();  // (5) V_r ready

  // ---- f_r2l = P_r @ V_r fused epilogue -> out0 ----
  pv_epi(prF, S1, xl, base, beta, out0, w, l16, quad);

  bf16x8 pcF[4];
#pragma unroll
  for (int ks = 0; ks < 4; ++ks)
    pcF[ks] = *(const bf16x8*)(S2 + eoff(row, ks * 32 + quad * 8));
  __syncthreads();  // (6) all pcF reads done before V_l overwrites S2

  // ---- V_l^T -> S2 (xlF dies) ----
  proj_g<1>(xlF, wT + 2 * 16384, S2, bvl, 1.0f, w, l16, quad);
  __syncthreads();  // (7) V_l ready

  // ---- f_l2r = P_c @ V_l fused epilogue -> out1 ----
  pv_epi(pcF, S2, xr, base, gamma, out1, w, l16, quad);
}

extern "C" void kernel_launch(void* const* d_in, const int* in_sizes, int n_in,
                              void* d_out, int out_size, void* d_ws, size_t ws_size,
                              hipStream_t stream) {
  const float* xl = (const float*)d_in[0];
  const float* xr = (const float*)d_in[1];
  const float* gl = (const float*)d_in[2];
  const float* bl = (const float*)d_in[3];
  const float* gr = (const float*)d_in[4];
  const float* br = (const float*)d_in[5];
  const float* wql = (const float*)d_in[6];
  const float* bql = (const float*)d_in[7];
  const float* wqr = (const float*)d_in[8];
  const float* bqr = (const float*)d_in[9];
  const float* wvl = (const float*)d_in[10];
  const float* bvl = (const float*)d_in[11];
  const float* wvr = (const float*)d_in[12];
  const float* bvr = (const float*)d_in[13];
  const float* beta = (const float*)d_in[14];
  const float* gamma = (const float*)d_in[15];

  __bf16* wT = (__bf16*)d_ws;          // 4 * 16384 bf16 = 128 KB scratch
  float* out0 = (float*)d_out;         // [8,128,128,128] fp32
  float* out1 = out0 + (size_t)8 * 128 * 128 * 128;

  prep_w<<<dim3(64, 4), 256, 0, stream>>>(wql, wqr, wvl, wvr, wT);
  scam_fused<<<1024, 512, 0, stream>>>(xl, xr, gl, bl, gr, br, wT, bql, bqr, bvl, bvr,
                                       beta, gamma, out0, out1);
}